// Round 3
// baseline (1268.611 us; speedup 1.0000x reference)
//
#include <hip/hip_runtime.h>
#include <math.h>

#define N_TOK 4096
#define DDIM  768
#define LDIM  256
#define VNUM  50265
#define VPAD  50304      // 786 tiles of 64 cols
#define NT64  786
#define NGRP  16
#define QBLK  256
#define KSEL  4
#define M3    3145728    // N_TOK*DDIM

// workspace layout (float offsets), total ~87 MB
#define WS_ZI_PRE 0
#define WS_ZI     (WS_ZI_PRE + N_TOK*LDIM)
#define WS_ZC     (WS_ZI + N_TOK*LDIM)
#define WS_ZCB    (WS_ZC + VPAD*LDIM)        // zc bf16 (VPAD*LDIM/2 float slots)
#define WS_QUANT  WS_ZCB                     // quant overlays zc_bf16 (dead after filter)
#define WS_CAND   (WS_ZCB + VPAD*LDIM/2)
#define WS_IDX    (WS_CAND + N_TOK*64)
#define WS_COUNTS (WS_IDX + N_TOK*4)
#define WS_ACCUM  (WS_COUNTS + VPAD)

typedef __attribute__((ext_vector_type(8))) short short8;
typedef __attribute__((ext_vector_type(4))) float f32x4;

__device__ __forceinline__ unsigned short f2bf(float f) {
    unsigned u = __float_as_uint(f);
    u += 0x7fffu + ((u >> 16) & 1u);
    return (unsigned short)(u >> 16);
}

__device__ __forceinline__ bool better(float v1, int i1, float v2, int i2) {
    return (v1 > v2) || (v1 == v2 && i1 < i2);
}

template<int K>
__device__ __forceinline__ void insertK(float (&v)[K], int (&ix)[K], float nv, int ni) {
    if (!better(nv, ni, v[K-1], ix[K-1])) return;
    v[K-1] = nv; ix[K-1] = ni;
    #pragma unroll
    for (int j = K-1; j > 0; j--) {
        if (better(v[j], ix[j], v[j-1], ix[j-1])) {
            float tv = v[j]; v[j] = v[j-1]; v[j-1] = tv;
            int ti = ix[j]; ix[j] = ix[j-1]; ix[j-1] = ti;
        } else break;
    }
}

// Generic C[M,256] = A[M,768] @ W[768,256] + bias, with epilogues:
// mode 1: write pre + l2-normalized
// mode 2: write normalized fp32 + bf16 (rows up to grid extent; buffers VPAD-sized)
// mode 3: accumulate sum((pre-target)^2) -> accum_slot
__global__ __launch_bounds__(256) void gemm_k(
    const float* __restrict__ A, const float* __restrict__ W,
    const float* __restrict__ bias, float* __restrict__ out_pre,
    float* __restrict__ out_norm, unsigned short* __restrict__ out_bf,
    const float* __restrict__ target, float* __restrict__ accum_slot,
    int M, int mode)
{
    __shared__ float a_s[32*64];    // [k][m]
    __shared__ float w_s[32*256];   // [k][n]
    const int tid = threadIdx.x;
    const int tx = tid & 31, ty = tid >> 5;
    const int mbase = blockIdx.x * 64;

    float acc[8][8];
    #pragma unroll
    for (int i = 0; i < 8; i++)
        #pragma unroll
        for (int j = 0; j < 8; j++) acc[i][j] = 0.f;

    for (int kk = 0; kk < DDIM; kk += 32) {
        __syncthreads();
        #pragma unroll
        for (int s = 0; s < 2; s++) {
            int slot = tid + s*256;
            int row = slot >> 3, kc = (slot & 7) << 2;
            int gr = mbase + row; if (gr >= M) gr = M - 1;
            float4 v = *(const float4*)&A[(size_t)gr*DDIM + kk + kc];
            a_s[(kc+0)*64 + row] = v.x;
            a_s[(kc+1)*64 + row] = v.y;
            a_s[(kc+2)*64 + row] = v.z;
            a_s[(kc+3)*64 + row] = v.w;
        }
        #pragma unroll
        for (int s = 0; s < 8; s++) {
            int slot = tid + s*256;
            int r = slot >> 6, c = (slot & 63) << 2;
            *(float4*)&w_s[r*256 + c] = *(const float4*)&W[(size_t)(kk + r)*LDIM + c];
        }
        __syncthreads();
        #pragma unroll
        for (int k = 0; k < 32; k++) {
            float4 a0 = *(float4*)&a_s[k*64 + ty*8];
            float4 a1 = *(float4*)&a_s[k*64 + ty*8 + 4];
            float4 w0 = *(float4*)&w_s[k*256 + tx*4];
            float4 w1 = *(float4*)&w_s[k*256 + 128 + tx*4];
            float am[8] = {a0.x,a0.y,a0.z,a0.w,a1.x,a1.y,a1.z,a1.w};
            float wn[8] = {w0.x,w0.y,w0.z,w0.w,w1.x,w1.y,w1.z,w1.w};
            #pragma unroll
            for (int i = 0; i < 8; i++)
                #pragma unroll
                for (int j = 0; j < 8; j++)
                    acc[i][j] = fmaf(am[i], wn[j], acc[i][j]);
        }
    }

    float bn[8];
    #pragma unroll
    for (int j = 0; j < 8; j++) {
        int col = (j < 4) ? (tx*4 + j) : (128 + tx*4 + (j-4));
        bn[j] = bias[col];
    }
    #pragma unroll
    for (int i = 0; i < 8; i++)
        #pragma unroll
        for (int j = 0; j < 8; j++) acc[i][j] += bn[j];

    if (mode == 1) {
        #pragma unroll
        for (int i = 0; i < 8; i++) {
            int gr = mbase + ty*8 + i;
            if (gr < M) {
                *(float4*)&out_pre[(size_t)gr*LDIM + tx*4] =
                    make_float4(acc[i][0], acc[i][1], acc[i][2], acc[i][3]);
                *(float4*)&out_pre[(size_t)gr*LDIM + 128 + tx*4] =
                    make_float4(acc[i][4], acc[i][5], acc[i][6], acc[i][7]);
            }
        }
    }
    if (mode == 1 || mode == 2) {
        #pragma unroll
        for (int i = 0; i < 8; i++) {
            float s = 0.f;
            #pragma unroll
            for (int j = 0; j < 8; j++) s += acc[i][j]*acc[i][j];
            #pragma unroll
            for (int m = 16; m >= 1; m >>= 1) s += __shfl_xor(s, m, 64);
            float sc = 1.0f / sqrtf(s + 1e-12f);
            int gr = mbase + ty*8 + i;
            bool wr = (mode == 2) || (gr < M);
            if (wr) {
                float p[8];
                #pragma unroll
                for (int j = 0; j < 8; j++) p[j] = acc[i][j]*sc;
                *(float4*)&out_norm[(size_t)gr*LDIM + tx*4] = make_float4(p[0],p[1],p[2],p[3]);
                *(float4*)&out_norm[(size_t)gr*LDIM + 128 + tx*4] = make_float4(p[4],p[5],p[6],p[7]);
                if (out_bf) {
                    ushort4 b0, b1;
                    b0.x = f2bf(p[0]); b0.y = f2bf(p[1]); b0.z = f2bf(p[2]); b0.w = f2bf(p[3]);
                    b1.x = f2bf(p[4]); b1.y = f2bf(p[5]); b1.z = f2bf(p[6]); b1.w = f2bf(p[7]);
                    *(ushort4*)&out_bf[(size_t)gr*LDIM + tx*4] = b0;
                    *(ushort4*)&out_bf[(size_t)gr*LDIM + 128 + tx*4] = b1;
                }
            }
        }
    }
    if (mode == 3) {
        float ls = 0.f;
        #pragma unroll
        for (int i = 0; i < 8; i++) {
            int gr = mbase + ty*8 + i;
            if (gr < M) {
                #pragma unroll
                for (int j = 0; j < 8; j++) {
                    int col = (j < 4) ? (tx*4 + j) : (128 + tx*4 + (j-4));
                    float dd = acc[i][j] - target[(size_t)gr*LDIM + col];
                    ls = fmaf(dd, dd, ls);
                }
            }
        }
        #pragma unroll
        for (int off = 32; off >= 1; off >>= 1) ls += __shfl_down(ls, off, 64);
        __syncthreads();
        if ((tid & 63) == 0) a_s[tid >> 6] = ls;
        __syncthreads();
        if (tid == 0) atomicAdd(accum_slot, a_s[0]+a_s[1]+a_s[2]+a_s[3]);
    }
}

// ---------------- bf16 MFMA filter, manually-pipelined ----------------
// Block: 8 waves x 32 resident queries = 256 q; cgroup g of 16.
// Chunk = 64 cols x 64 k bf16 (8 KB), 4-buffer LDS ring, 3 chunks in flight,
// raw s_waitcnt(vmcnt(2)) + s_barrier (no compiler vmcnt(0) drain).
// LDS k-segments XOR-swizzled (slot = seg ^ (col&7)) at the load side.

__device__ __forceinline__ void stage_chunk(
    const unsigned short* __restrict__ zcb, unsigned char* smem,
    int ci, int wave, int lane, int g)
{
    const int T  = g + (ci >> 2) * NGRP;        // 64-col tile id
    const int kc = ci & 3;                      // 64-k chunk
    const int r_local = wave*8 + (lane >> 3);   // 0..63 (col within tile)
    const int sg = (lane & 7) ^ (lane >> 3);    // swizzled global k-seg
    const unsigned short* gp = zcb + (size_t)(T*64 + r_local)*LDIM + kc*64 + sg*8;
    unsigned char* lp = smem + (ci & 3)*8192 + wave*1024 + lane*16;
    __builtin_amdgcn_global_load_lds(
        (const __attribute__((address_space(1))) void*)gp,
        (__attribute__((address_space(3))) void*)lp, 16, 0, 0);
}

__global__ __launch_bounds__(512, 2) void filter_kernel(
    const float* __restrict__ zi, const unsigned short* __restrict__ zcb,
    int* __restrict__ cand)
{
    __shared__ unsigned char smem[32768];       // 4 x 8KB ring
    const int tid = threadIdx.x;
    const int wave = tid >> 6, lane = tid & 63;
    const int l15 = lane & 15, l4 = lane >> 4;
    const int qbase = blockIdx.x * QBLK + wave * 32;
    const int g = blockIdx.y;                   // 0..15

    // A fragments (zi cast to bf16) resident: [qtile][kstep]
    short8 afrag[2][8];
    #pragma unroll
    for (int qt = 0; qt < 2; qt++)
        #pragma unroll
        for (int ks = 0; ks < 8; ks++) {
            const float* src = zi + (size_t)(qbase + qt*16 + l15)*LDIM + ks*32 + l4*8;
            float4 v0 = *(const float4*)src;
            float4 v1 = *(const float4*)(src + 4);
            short8 a;
            a[0] = (short)f2bf(v0.x); a[1] = (short)f2bf(v0.y);
            a[2] = (short)f2bf(v0.z); a[3] = (short)f2bf(v0.w);
            a[4] = (short)f2bf(v1.x); a[5] = (short)f2bf(v1.y);
            a[6] = (short)f2bf(v1.z); a[7] = (short)f2bf(v1.w);
            afrag[qt][ks] = a;
        }

    float tv[2][4][3]; int tix[2][4][3];
    #pragma unroll
    for (int qt = 0; qt < 2; qt++)
        #pragma unroll
        for (int rr = 0; rr < 4; rr++)
            #pragma unroll
            for (int j = 0; j < 3; j++) { tv[qt][rr][j] = -1e30f; tix[qt][rr][j] = 0x7fffffff; }

    f32x4 acc[2][4];
    #pragma unroll
    for (int qt = 0; qt < 2; qt++)
        #pragma unroll
        for (int tc = 0; tc < 4; tc++) acc[qt][tc] = (f32x4)(0.f);

    const int nct = (g < 2) ? 50 : 49;          // 786 = 49*16 + 2
    const int NCk = nct * 4;                    // k-chunks total (multiple of 4)

    stage_chunk(zcb, smem, 0, wave, lane, g);
    stage_chunk(zcb, smem, 1, wave, lane, g);
    stage_chunk(zcb, smem, 2, wave, lane, g);

    for (int ci = 0; ci < NCk; ci++) {
        __builtin_amdgcn_s_waitcnt(0x0F72);     // vmcnt(2): chunk ci landed
        __builtin_amdgcn_s_barrier();
        asm volatile("" ::: "memory");
        int nx = ci + 3; if (nx >= NCk) nx -= NCk;   // harmless wrap re-stage
        stage_chunk(zcb, smem, nx, wave, lane, g);

        const unsigned short* lb = (const unsigned short*)(smem + (ci & 3)*8192);
        const int kc = ci & 3;
        #pragma unroll
        for (int ks2 = 0; ks2 < 2; ks2++) {
            const int kf = kc*2 + ks2;
            #pragma unroll
            for (int tc = 0; tc < 4; tc++) {
                const int c = tc*16 + l15;
                const int slot = (ks2*4 + l4) ^ (c & 7);
                const short8 b = *(const short8*)&lb[c*64 + slot*8];
                acc[0][tc] = __builtin_amdgcn_mfma_f32_16x16x32_bf16(afrag[0][kf], b, acc[0][tc], 0, 0, 0);
                acc[1][tc] = __builtin_amdgcn_mfma_f32_16x16x32_bf16(afrag[1][kf], b, acc[1][tc], 0, 0, 0);
            }
        }

        if ((ci & 3) == 3) {                    // tile finished (k=256 done)
            const int T = g + (ci >> 2)*NGRP;
            #pragma unroll
            for (int tc = 0; tc < 4; tc++) {
                const int col = T*64 + tc*16 + l15;
                const bool ok = col < VNUM;
                #pragma unroll
                for (int qt = 0; qt < 2; qt++) {
                    #pragma unroll
                    for (int rr = 0; rr < 4; rr++) {
                        float v = acc[qt][tc][rr];
                        if (ok) insertK<3>(tv[qt][rr], tix[qt][rr], v, col);
                    }
                    acc[qt][tc] = (f32x4)(0.f);
                }
            }
        }
    }

    // merge per-lane-class top-3 across the 16 col-lanes (butterfly in-quad)
    #pragma unroll
    for (int qt = 0; qt < 2; qt++)
        #pragma unroll
        for (int rr = 0; rr < 4; rr++) {
            float mv[4] = { tv[qt][rr][0], tv[qt][rr][1], tv[qt][rr][2], -1e30f };
            int   mi[4] = { tix[qt][rr][0], tix[qt][rr][1], tix[qt][rr][2], 0x7fffffff };
            #pragma unroll
            for (int m = 1; m < 16; m <<= 1) {
                float ov[4]; int oi[4];
                #pragma unroll
                for (int s = 0; s < 4; s++) {
                    ov[s] = __shfl_xor(mv[s], m, 64);
                    oi[s] = __shfl_xor(mi[s], m, 64);
                }
                #pragma unroll
                for (int s = 0; s < 4; s++) insertK<4>(mv, mi, ov[s], oi[s]);
            }
            if (l15 == 0) {
                const int q = qbase + qt*16 + l4*4 + rr;
                #pragma unroll
                for (int j = 0; j < 4; j++) cand[(size_t)q*64 + g*4 + j] = mi[j];
            }
        }
}

// exact fp32 rescore of 64 candidates/query; top-4 with ref tie-breaking
__global__ __launch_bounds__(256) void rescore_kernel(
    const float* __restrict__ zi, const float* __restrict__ zc,
    const int* __restrict__ cand, int* __restrict__ idx4)
{
    __shared__ float zi_s[256];
    __shared__ float sval[64];
    __shared__ int   sidx[64];
    const int q = blockIdx.x;
    const int t = threadIdx.x;
    if (t < 64) *(float4*)&zi_s[t*4] = *(const float4*)&zi[(size_t)q*LDIM + t*4];
    __syncthreads();

    const int j = t >> 2, l4 = t & 3;
    int idx = cand[(size_t)q*64 + j];
    const bool valid = (unsigned)idx < (unsigned)VNUM;
    const float* r = zc + (size_t)(valid ? idx : 0)*LDIM;
    float dot = 0.f, nsq = 0.f;
    #pragma unroll
    for (int i = 0; i < 16; i++) {
        float4 v = *(const float4*)&r[i*16 + l4*4];
        float4 z = *(const float4*)&zi_s[i*16 + l4*4];
        dot = fmaf(v.x, z.x, fmaf(v.y, z.y, fmaf(v.z, z.z, fmaf(v.w, z.w, dot))));
        nsq = fmaf(v.x, v.x, fmaf(v.y, v.y, fmaf(v.z, v.z, fmaf(v.w, v.w, nsq))));
    }
    dot += __shfl_xor(dot, 1, 64); dot += __shfl_xor(dot, 2, 64);
    nsq += __shfl_xor(nsq, 1, 64); nsq += __shfl_xor(nsq, 2, 64);
    const float sc = valid ? (dot - 0.5f*nsq) : -1e30f;
    if (l4 == 0) { sval[j] = sc; sidx[j] = valid ? idx : 0x7fffffff; }
    __syncthreads();

    if (t < 64) {
        float v[4] = {-1e30f, -1e30f, -1e30f, -1e30f};
        int ix[4] = {0x7fffffff, 0x7fffffff, 0x7fffffff, 0x7fffffff};
        insertK<4>(v, ix, sval[t], sidx[t]);
        #pragma unroll
        for (int m = 1; m < 64; m <<= 1) {
            float ov[4]; int oi[4];
            #pragma unroll
            for (int s = 0; s < 4; s++) {
                ov[s] = __shfl_xor(v[s], m, 64);
                oi[s] = __shfl_xor(ix[s], m, 64);
            }
            #pragma unroll
            for (int s = 0; s < 4; s++) insertK<4>(v, ix, ov[s], oi[s]);
        }
        if (t == 0) {
            #pragma unroll
            for (int s = 0; s < 4; s++) idx4[q*4 + s] = ix[s];
        }
    }
}

// gather codes, mean-of-4, STE out, counts atomics, loss1 partial
__global__ __launch_bounds__(192) void gather_kernel(
    const float* __restrict__ x, const float* __restrict__ cb,
    const int* __restrict__ idx4, float* __restrict__ quant,
    float* __restrict__ out, float* __restrict__ counts,
    float* __restrict__ accum)
{
    __shared__ float red[3];
    const int n = blockIdx.x;
    const int t = threadIdx.x;
    const int i0 = idx4[n*4+0], i1 = idx4[n*4+1], i2 = idx4[n*4+2], i3 = idx4[n*4+3];
    if (t < 4) atomicAdd(&counts[idx4[n*4+t]], 1.0f);
    const int d = t*4;
    float4 c0 = *(const float4*)&cb[(size_t)i0*DDIM + d];
    float4 c1 = *(const float4*)&cb[(size_t)i1*DDIM + d];
    float4 c2 = *(const float4*)&cb[(size_t)i2*DDIM + d];
    float4 c3 = *(const float4*)&cb[(size_t)i3*DDIM + d];
    float4 xv = *(const float4*)&x[(size_t)n*DDIM + d];
    float4 qv;
    qv.x = (((c0.x + c1.x) + c2.x) + c3.x) * 0.25f;
    qv.y = (((c0.y + c1.y) + c2.y) + c3.y) * 0.25f;
    qv.z = (((c0.z + c1.z) + c2.z) + c3.z) * 0.25f;
    qv.w = (((c0.w + c1.w) + c2.w) + c3.w) * 0.25f;
    float4 o;
    o.x = xv.x + (qv.x - xv.x);
    o.y = xv.y + (qv.y - xv.y);
    o.z = xv.z + (qv.z - xv.z);
    o.w = xv.w + (qv.w - xv.w);
    *(float4*)&quant[(size_t)n*DDIM + d] = qv;
    *(float4*)&out[(size_t)n*DDIM + d] = o;
    float d0 = qv.x - xv.x, d1 = qv.y - xv.y, d2 = qv.z - xv.z, d3 = qv.w - xv.w;
    float ls = d0*d0 + d1*d1 + d2*d2 + d3*d3;
    #pragma unroll
    for (int off = 32; off >= 1; off >>= 1) ls += __shfl_down(ls, off, 64);
    if ((t & 63) == 0) red[t >> 6] = ls;
    __syncthreads();
    if (t == 0) atomicAdd(accum, red[0] + red[1] + red[2]);
}

__global__ __launch_bounds__(256) void stats_kernel(
    const float* __restrict__ counts, float* __restrict__ accum)
{
    __shared__ float redE[4], redN[4];
    int v = blockIdx.x*256 + threadIdx.x;
    float ent = 0.f, nnz = 0.f;
    if (v < VNUM) {
        float c = counts[v];
        if (c > 0.f) {
            float p = c * (1.0f/16384.0f);
            ent = p * logf(p + 1e-10f);
            nnz = 1.f;
        }
    }
    #pragma unroll
    for (int off = 32; off >= 1; off >>= 1) {
        ent += __shfl_down(ent, off, 64);
        nnz += __shfl_down(nnz, off, 64);
    }
    int t = threadIdx.x;
    if ((t & 63) == 0) { redE[t>>6] = ent; redN[t>>6] = nnz; }
    __syncthreads();
    if (t == 0) {
        atomicAdd(accum+2, redE[0]+redE[1]+redE[2]+redE[3]);
        atomicAdd(accum+3, redN[0]+redN[1]+redN[2]+redN[3]);
    }
}

__global__ void final_kernel(const float* __restrict__ accum, float* __restrict__ out)
{
    float logp = -accum[2];
    float m1 = accum[0] * (1.0f / (float)M3);
    float m2 = accum[1] * (1.0f / (float)(N_TOK*LDIM));
    float loss = (m1*0.25f + m1) + (m2*0.25f + m2) + 0.1f*logp;
    out[M3+0] = loss;
    out[M3+1] = expf(logp);
    out[M3+2] = (accum[3] / (float)VNUM) / (float)KSEL;
}

extern "C" void kernel_launch(void* const* d_in, const int* in_sizes, int n_in,
                              void* d_out, int out_size, void* d_ws, size_t ws_size,
                              hipStream_t stream)
{
    const float* x      = (const float*)d_in[0];
    const float* cb     = (const float*)d_in[1];
    const float* W_in   = (const float*)d_in[2];
    const float* b_in   = (const float*)d_in[3];
    const float* W_code = (const float*)d_in[4];
    const float* b_code = (const float*)d_in[5];
    float* out = (float*)d_out;
    float* w   = (float*)d_ws;

    float* zi_pre = w + WS_ZI_PRE;
    float* zi     = w + WS_ZI;
    float* zc     = w + WS_ZC;
    unsigned short* zcb = (unsigned short*)(w + WS_ZCB);
    float* quant  = w + WS_QUANT;
    int*   cand   = (int*)(w + WS_CAND);
    int*   idx4   = (int*)(w + WS_IDX);
    float* counts = w + WS_COUNTS;
    float* accum  = w + WS_ACCUM;

    hipMemsetAsync(counts, 0, (VPAD + 8)*sizeof(float), stream);

    // zi_pre / zi (fp32, exact path)
    gemm_k<<<N_TOK/64, 256, 0, stream>>>(x, W_in, b_in, zi_pre, zi, nullptr,
                                         nullptr, nullptr, N_TOK, 1);
    // zc fp32 (exact path) + zc bf16 (filter path)
    gemm_k<<<VPAD/64, 256, 0, stream>>>(cb, W_code, b_code, nullptr, zc, zcb,
                                        nullptr, nullptr, VNUM, 2);
    // bf16 MFMA candidate filter (pipelined)
    filter_kernel<<<dim3(N_TOK/QBLK, NGRP), 512, 0, stream>>>(zi, zcb, cand);
    // exact fp32 rescore -> top-4 indices
    rescore_kernel<<<N_TOK, 256, 0, stream>>>(zi, zc, cand, idx4);
    // quantized, out (STE), counts, loss1  (quant overlays dead zc_bf16)
    gather_kernel<<<N_TOK, 192, 0, stream>>>(x, cb, idx4, quant, out, counts, accum);
    // entropy / usage
    stats_kernel<<<(VNUM + 255)/256, 256, 0, stream>>>(counts, accum);
    // loss2: sum((quant@W_code+b_code - zi_pre)^2)
    gemm_k<<<N_TOK/64, 256, 0, stream>>>(quant, W_code, b_code, nullptr, nullptr, nullptr,
                                         zi_pre, accum+1, N_TOK, 3);
    final_kernel<<<1, 1, 0, stream>>>(accum, out);
}

// Round 4
// 1240.090 us; speedup vs baseline: 1.0230x; 1.0230x over previous
//
#include <hip/hip_runtime.h>
#include <math.h>

#define N_TOK 4096
#define DDIM  768
#define LDIM  256
#define VNUM  50265
#define VPAD  50304      // 786 tiles of 64 cols
#define NT64  786
#define NGRP  16
#define QBLK  256
#define KSEL  4
#define M3    3145728    // N_TOK*DDIM

// workspace layout (float offsets), total ~89 MB
#define WS_ZI_PRE 0
#define WS_ZI     (WS_ZI_PRE + N_TOK*LDIM)
#define WS_ZIB    (WS_ZI + N_TOK*LDIM)               // zi bf16 (N_TOK*LDIM/2 floats)
#define WS_ZC     (WS_ZIB + N_TOK*LDIM/2)
#define WS_ZCB    (WS_ZC + VPAD*LDIM)                // zc bf16, tiled+swizzled
#define WS_QUANT  WS_ZCB                             // quant overlays zcb (dead after filter)
#define WS_CAND   (WS_ZCB + VPAD*LDIM/2)
#define WS_IDX    (WS_CAND + N_TOK*64)
#define WS_COUNTS (WS_IDX + N_TOK*4)
#define WS_ACCUM  (WS_COUNTS + VPAD)

typedef __attribute__((ext_vector_type(8))) short short8;
typedef __attribute__((ext_vector_type(4))) float f32x4;

__device__ __forceinline__ unsigned short f2bf(float f) {
    unsigned u = __float_as_uint(f);
    u += 0x7fffu + ((u >> 16) & 1u);
    return (unsigned short)(u >> 16);
}

__device__ __forceinline__ bool better(float v1, int i1, float v2, int i2) {
    return (v1 > v2) || (v1 == v2 && i1 < i2);
}

template<int K>
__device__ __forceinline__ void insertK(float (&v)[K], int (&ix)[K], float nv, int ni) {
    if (!better(nv, ni, v[K-1], ix[K-1])) return;
    v[K-1] = nv; ix[K-1] = ni;
    #pragma unroll
    for (int j = K-1; j > 0; j--) {
        if (better(v[j], ix[j], v[j-1], ix[j-1])) {
            float tv = v[j]; v[j] = v[j-1]; v[j-1] = tv;
            int ti = ix[j]; ix[j] = ix[j-1]; ix[j-1] = ti;
        } else break;
    }
}

// Generic C[M,256] = A[M,768] @ W[768,256] + bias, with epilogues:
// mode 1: write pre + l2-normalized fp32 + plain row-major bf16
// mode 2: write normalized fp32 + bf16 in TILED+SWIZZLED chunk layout
//         (rows up to grid extent; buffers VPAD-sized)
// mode 3: accumulate sum((pre-target)^2) -> accum_slot
__global__ __launch_bounds__(256) void gemm_k(
    const float* __restrict__ A, const float* __restrict__ W,
    const float* __restrict__ bias, float* __restrict__ out_pre,
    float* __restrict__ out_norm, unsigned short* __restrict__ out_bf,
    const float* __restrict__ target, float* __restrict__ accum_slot,
    int M, int mode)
{
    __shared__ float a_s[32*64];    // [k][m]
    __shared__ float w_s[32*256];   // [k][n]
    const int tid = threadIdx.x;
    const int tx = tid & 31, ty = tid >> 5;
    const int mbase = blockIdx.x * 64;

    float acc[8][8];
    #pragma unroll
    for (int i = 0; i < 8; i++)
        #pragma unroll
        for (int j = 0; j < 8; j++) acc[i][j] = 0.f;

    for (int kk = 0; kk < DDIM; kk += 32) {
        __syncthreads();
        #pragma unroll
        for (int s = 0; s < 2; s++) {
            int slot = tid + s*256;
            int row = slot >> 3, kc = (slot & 7) << 2;
            int gr = mbase + row; if (gr >= M) gr = M - 1;
            float4 v = *(const float4*)&A[(size_t)gr*DDIM + kk + kc];
            a_s[(kc+0)*64 + row] = v.x;
            a_s[(kc+1)*64 + row] = v.y;
            a_s[(kc+2)*64 + row] = v.z;
            a_s[(kc+3)*64 + row] = v.w;
        }
        #pragma unroll
        for (int s = 0; s < 8; s++) {
            int slot = tid + s*256;
            int r = slot >> 6, c = (slot & 63) << 2;
            *(float4*)&w_s[r*256 + c] = *(const float4*)&W[(size_t)(kk + r)*LDIM + c];
        }
        __syncthreads();
        #pragma unroll
        for (int k = 0; k < 32; k++) {
            float4 a0 = *(float4*)&a_s[k*64 + ty*8];
            float4 a1 = *(float4*)&a_s[k*64 + ty*8 + 4];
            float4 w0 = *(float4*)&w_s[k*256 + tx*4];
            float4 w1 = *(float4*)&w_s[k*256 + 128 + tx*4];
            float am[8] = {a0.x,a0.y,a0.z,a0.w,a1.x,a1.y,a1.z,a1.w};
            float wn[8] = {w0.x,w0.y,w0.z,w0.w,w1.x,w1.y,w1.z,w1.w};
            #pragma unroll
            for (int i = 0; i < 8; i++)
                #pragma unroll
                for (int j = 0; j < 8; j++)
                    acc[i][j] = fmaf(am[i], wn[j], acc[i][j]);
        }
    }

    float bn[8];
    #pragma unroll
    for (int j = 0; j < 8; j++) {
        int col = (j < 4) ? (tx*4 + j) : (128 + tx*4 + (j-4));
        bn[j] = bias[col];
    }
    #pragma unroll
    for (int i = 0; i < 8; i++)
        #pragma unroll
        for (int j = 0; j < 8; j++) acc[i][j] += bn[j];

    if (mode == 1) {
        #pragma unroll
        for (int i = 0; i < 8; i++) {
            int gr = mbase + ty*8 + i;
            if (gr < M) {
                *(float4*)&out_pre[(size_t)gr*LDIM + tx*4] =
                    make_float4(acc[i][0], acc[i][1], acc[i][2], acc[i][3]);
                *(float4*)&out_pre[(size_t)gr*LDIM + 128 + tx*4] =
                    make_float4(acc[i][4], acc[i][5], acc[i][6], acc[i][7]);
            }
        }
    }
    if (mode == 1 || mode == 2) {
        #pragma unroll
        for (int i = 0; i < 8; i++) {
            float s = 0.f;
            #pragma unroll
            for (int j = 0; j < 8; j++) s += acc[i][j]*acc[i][j];
            #pragma unroll
            for (int m = 16; m >= 1; m >>= 1) s += __shfl_xor(s, m, 64);
            float sc = 1.0f / sqrtf(s + 1e-12f);
            int gr = mbase + ty*8 + i;
            bool wr = (mode == 2) || (gr < M);
            if (wr) {
                float p[8];
                #pragma unroll
                for (int j = 0; j < 8; j++) p[j] = acc[i][j]*sc;
                *(float4*)&out_norm[(size_t)gr*LDIM + tx*4] = make_float4(p[0],p[1],p[2],p[3]);
                *(float4*)&out_norm[(size_t)gr*LDIM + 128 + tx*4] = make_float4(p[4],p[5],p[6],p[7]);
                if (out_bf) {
                    ushort4 b0, b1;
                    b0.x = f2bf(p[0]); b0.y = f2bf(p[1]); b0.z = f2bf(p[2]); b0.w = f2bf(p[3]);
                    b1.x = f2bf(p[4]); b1.y = f2bf(p[5]); b1.z = f2bf(p[6]); b1.w = f2bf(p[7]);
                    if (mode == 1) {
                        *(ushort4*)&out_bf[(size_t)gr*LDIM + tx*4] = b0;
                        *(ushort4*)&out_bf[(size_t)gr*LDIM + 128 + tx*4] = b1;
                    } else {
                        // tiled+swizzled: chunk ck=(T*4+kc) is 8KB contiguous;
                        // slot(c,seg) = c*8 + (seg ^ (c&7)), 8 elems each.
                        const int T = gr >> 6, c = gr & 63;
                        #pragma unroll
                        for (int h = 0; h < 2; h++) {
                            const int k0 = h*128 + tx*4;
                            const int kc = k0 >> 6, seg = (k0 >> 3) & 7, e = k0 & 7;
                            const int slot = c*8 + (seg ^ (c & 7));
                            size_t idx = ((size_t)(T*4 + kc))*4096 + slot*8 + e;
                            *(ushort4*)&out_bf[idx] = h ? b1 : b0;
                        }
                    }
                }
            }
        }
    }
    if (mode == 3) {
        float ls = 0.f;
        #pragma unroll
        for (int i = 0; i < 8; i++) {
            int gr = mbase + ty*8 + i;
            if (gr < M) {
                #pragma unroll
                for (int j = 0; j < 8; j++) {
                    int col = (j < 4) ? (tx*4 + j) : (128 + tx*4 + (j-4));
                    float dd = acc[i][j] - target[(size_t)gr*LDIM + col];
                    ls = fmaf(dd, dd, ls);
                }
            }
        }
        #pragma unroll
        for (int off = 32; off >= 1; off >>= 1) ls += __shfl_down(ls, off, 64);
        __syncthreads();
        if ((tid & 63) == 0) a_s[tid >> 6] = ls;
        __syncthreads();
        if (tid == 0) atomicAdd(accum_slot, a_s[0]+a_s[1]+a_s[2]+a_s[3]);
    }
}

// ---------------- bf16 MFMA filter, reg->ds_write double-buffer ----------------
// Block: 8 waves x 32 q = 256 q; cgroup g of 16 (tiles strided by 16).
// Chunk = 64 cols x 64 k bf16 = 8 KB, contiguous+pre-swizzled in zcb.
// Pipeline: load next chunk to regs at iter start (hidden under 16 MFMA/wave),
// then barrier / ds_write / barrier. No global_load_lds (avoids LDS-DMA waits).
__global__ __launch_bounds__(512, 2) __attribute__((amdgpu_waves_per_eu(2, 2)))
void filter_kernel(
    const unsigned short* __restrict__ zib, const unsigned short* __restrict__ zcb,
    int* __restrict__ cand)
{
    __shared__ unsigned short lds[2*4096];      // 2 x 8 KB
    const int tid = threadIdx.x;
    const int wave = tid >> 6, lane = tid & 63;
    const int l15 = lane & 15, l4 = lane >> 4;
    const int qbase = blockIdx.x * QBLK + wave * 32;
    const int g = blockIdx.y;                   // 0..15

    // A fragments (zi bf16) resident: [qtile][kstep], 64 VGPRs
    short8 afrag[2][8];
    #pragma unroll
    for (int qt = 0; qt < 2; qt++)
        #pragma unroll
        for (int ks = 0; ks < 8; ks++)
            afrag[qt][ks] = *(const short8*)&zib[(size_t)(qbase + qt*16 + l15)*LDIM + ks*32 + l4*8];

    float tv[2][4][3]; int tix[2][4][3];
    #pragma unroll
    for (int qt = 0; qt < 2; qt++)
        #pragma unroll
        for (int rr = 0; rr < 4; rr++)
            #pragma unroll
            for (int j = 0; j < 3; j++) { tv[qt][rr][j] = -1e30f; tix[qt][rr][j] = 0x7fffffff; }

    f32x4 acc[2][4];
    #pragma unroll
    for (int qt = 0; qt < 2; qt++)
        #pragma unroll
        for (int tc = 0; tc < 4; tc++) acc[qt][tc] = (f32x4)(0.f);

    const int nct = (g < 2) ? 50 : 49;          // 786 = 49*16 + 2
    const int NCk = nct * 4;

    // chunk ci -> ushort offset (8KB contiguous chunks, pre-swizzled)
    #define CHUNK_OFF(ci) ((size_t)((g + ((ci) >> 2)*NGRP)*4 + ((ci) & 3)) * 4096)

    uint4 breg = *(const uint4*)&zcb[CHUNK_OFF(0) + tid*8];
    *(uint4*)&lds[tid*8] = breg;
    breg = *(const uint4*)&zcb[CHUNK_OFF(1) + tid*8];
    __syncthreads();

    for (int ci = 0; ci < NCk; ci++) {
        const unsigned short* lb = &lds[(ci & 1)*4096];
        #pragma unroll
        for (int ks2 = 0; ks2 < 2; ks2++) {
            const int kf = (ci & 3)*2 + ks2;
            #pragma unroll
            for (int tc = 0; tc < 4; tc++) {
                const int c = tc*16 + l15;
                const int slot = c*8 + ((ks2*4 + l4) ^ (c & 7));
                const short8 b = *(const short8*)&lb[slot*8];
                acc[0][tc] = __builtin_amdgcn_mfma_f32_16x16x32_bf16(afrag[0][kf], b, acc[0][tc], 0, 0, 0);
                acc[1][tc] = __builtin_amdgcn_mfma_f32_16x16x32_bf16(afrag[1][kf], b, acc[1][tc], 0, 0, 0);
            }
        }

        if ((ci & 3) == 3) {                    // tile finished (k=256 done)
            const int T = g + (ci >> 2)*NGRP;
            #pragma unroll
            for (int tc = 0; tc < 4; tc++) {
                const int col = T*64 + tc*16 + l15;
                const bool ok = col < VNUM;
                #pragma unroll
                for (int qt = 0; qt < 2; qt++) {
                    #pragma unroll
                    for (int rr = 0; rr < 4; rr++) {
                        float v = acc[qt][tc][rr];
                        if (ok) insertK<3>(tv[qt][rr], tix[qt][rr], v, col);
                    }
                    acc[qt][tc] = (f32x4)(0.f);
                }
            }
        }

        __syncthreads();                        // readers of other buffer done
        if (ci + 1 < NCk) {
            *(uint4*)&lds[((ci+1) & 1)*4096 + tid*8] = breg;
            if (ci + 2 < NCk) breg = *(const uint4*)&zcb[CHUNK_OFF(ci+2) + tid*8];
            __syncthreads();                    // next buffer ready
        }
    }
    #undef CHUNK_OFF

    // merge per-lane-class top-3 across the 16 col-lanes (butterfly in-quad)
    #pragma unroll
    for (int qt = 0; qt < 2; qt++)
        #pragma unroll
        for (int rr = 0; rr < 4; rr++) {
            float mv[4] = { tv[qt][rr][0], tv[qt][rr][1], tv[qt][rr][2], -1e30f };
            int   mi[4] = { tix[qt][rr][0], tix[qt][rr][1], tix[qt][rr][2], 0x7fffffff };
            #pragma unroll
            for (int m = 1; m < 16; m <<= 1) {
                float ov[4]; int oi[4];
                #pragma unroll
                for (int s = 0; s < 4; s++) {
                    ov[s] = __shfl_xor(mv[s], m, 64);
                    oi[s] = __shfl_xor(mi[s], m, 64);
                }
                #pragma unroll
                for (int s = 0; s < 4; s++) insertK<4>(mv, mi, ov[s], oi[s]);
            }
            if (l15 == 0) {
                const int q = qbase + qt*16 + l4*4 + rr;
                #pragma unroll
                for (int j = 0; j < 4; j++) cand[(size_t)q*64 + g*4 + j] = mi[j];
            }
        }
}

// exact fp32 rescore of 64 candidates/query; top-4 with ref tie-breaking
__global__ __launch_bounds__(256) void rescore_kernel(
    const float* __restrict__ zi, const float* __restrict__ zc,
    const int* __restrict__ cand, int* __restrict__ idx4)
{
    __shared__ float zi_s[256];
    __shared__ float sval[64];
    __shared__ int   sidx[64];
    const int q = blockIdx.x;
    const int t = threadIdx.x;
    if (t < 64) *(float4*)&zi_s[t*4] = *(const float4*)&zi[(size_t)q*LDIM + t*4];
    __syncthreads();

    const int j = t >> 2, l4 = t & 3;
    int idx = cand[(size_t)q*64 + j];
    const bool valid = (unsigned)idx < (unsigned)VNUM;
    const float* r = zc + (size_t)(valid ? idx : 0)*LDIM;
    float dot = 0.f, nsq = 0.f;
    #pragma unroll
    for (int i = 0; i < 16; i++) {
        float4 v = *(const float4*)&r[i*16 + l4*4];
        float4 z = *(const float4*)&zi_s[i*16 + l4*4];
        dot = fmaf(v.x, z.x, fmaf(v.y, z.y, fmaf(v.z, z.z, fmaf(v.w, z.w, dot))));
        nsq = fmaf(v.x, v.x, fmaf(v.y, v.y, fmaf(v.z, v.z, fmaf(v.w, v.w, nsq))));
    }
    dot += __shfl_xor(dot, 1, 64); dot += __shfl_xor(dot, 2, 64);
    nsq += __shfl_xor(nsq, 1, 64); nsq += __shfl_xor(nsq, 2, 64);
    const float sc = valid ? (dot - 0.5f*nsq) : -1e30f;
    if (l4 == 0) { sval[j] = sc; sidx[j] = valid ? idx : 0x7fffffff; }
    __syncthreads();

    if (t < 64) {
        float v[4] = {-1e30f, -1e30f, -1e30f, -1e30f};
        int ix[4] = {0x7fffffff, 0x7fffffff, 0x7fffffff, 0x7fffffff};
        insertK<4>(v, ix, sval[t], sidx[t]);
        #pragma unroll
        for (int m = 1; m < 64; m <<= 1) {
            float ov[4]; int oi[4];
            #pragma unroll
            for (int s = 0; s < 4; s++) {
                ov[s] = __shfl_xor(v[s], m, 64);
                oi[s] = __shfl_xor(ix[s], m, 64);
            }
            #pragma unroll
            for (int s = 0; s < 4; s++) insertK<4>(v, ix, ov[s], oi[s]);
        }
        if (t == 0) {
            #pragma unroll
            for (int s = 0; s < 4; s++) idx4[q*4 + s] = ix[s];
        }
    }
}

// gather codes, mean-of-4, STE out, counts atomics, loss1 partial
__global__ __launch_bounds__(192) void gather_kernel(
    const float* __restrict__ x, const float* __restrict__ cb,
    const int* __restrict__ idx4, float* __restrict__ quant,
    float* __restrict__ out, float* __restrict__ counts,
    float* __restrict__ accum)
{
    __shared__ float red[3];
    const int n = blockIdx.x;
    const int t = threadIdx.x;
    const int i0 = idx4[n*4+0], i1 = idx4[n*4+1], i2 = idx4[n*4+2], i3 = idx4[n*4+3];
    if (t < 4) atomicAdd(&counts[idx4[n*4+t]], 1.0f);
    const int d = t*4;
    float4 c0 = *(const float4*)&cb[(size_t)i0*DDIM + d];
    float4 c1 = *(const float4*)&cb[(size_t)i1*DDIM + d];
    float4 c2 = *(const float4*)&cb[(size_t)i2*DDIM + d];
    float4 c3 = *(const float4*)&cb[(size_t)i3*DDIM + d];
    float4 xv = *(const float4*)&x[(size_t)n*DDIM + d];
    float4 qv;
    qv.x = (((c0.x + c1.x) + c2.x) + c3.x) * 0.25f;
    qv.y = (((c0.y + c1.y) + c2.y) + c3.y) * 0.25f;
    qv.z = (((c0.z + c1.z) + c2.z) + c3.z) * 0.25f;
    qv.w = (((c0.w + c1.w) + c2.w) + c3.w) * 0.25f;
    float4 o;
    o.x = xv.x + (qv.x - xv.x);
    o.y = xv.y + (qv.y - xv.y);
    o.z = xv.z + (qv.z - xv.z);
    o.w = xv.w + (qv.w - xv.w);
    *(float4*)&quant[(size_t)n*DDIM + d] = qv;
    *(float4*)&out[(size_t)n*DDIM + d] = o;
    float d0 = qv.x - xv.x, d1 = qv.y - xv.y, d2 = qv.z - xv.z, d3 = qv.w - xv.w;
    float ls = d0*d0 + d1*d1 + d2*d2 + d3*d3;
    #pragma unroll
    for (int off = 32; off >= 1; off >>= 1) ls += __shfl_down(ls, off, 64);
    if ((t & 63) == 0) red[t >> 6] = ls;
    __syncthreads();
    if (t == 0) atomicAdd(accum, red[0] + red[1] + red[2]);
}

__global__ __launch_bounds__(256) void stats_kernel(
    const float* __restrict__ counts, float* __restrict__ accum)
{
    __shared__ float redE[4], redN[4];
    int v = blockIdx.x*256 + threadIdx.x;
    float ent = 0.f, nnz = 0.f;
    if (v < VNUM) {
        float c = counts[v];
        if (c > 0.f) {
            float p = c * (1.0f/16384.0f);
            ent = p * logf(p + 1e-10f);
            nnz = 1.f;
        }
    }
    #pragma unroll
    for (int off = 32; off >= 1; off >>= 1) {
        ent += __shfl_down(ent, off, 64);
        nnz += __shfl_down(nnz, off, 64);
    }
    int t = threadIdx.x;
    if ((t & 63) == 0) { redE[t>>6] = ent; redN[t>>6] = nnz; }
    __syncthreads();
    if (t == 0) {
        atomicAdd(accum+2, redE[0]+redE[1]+redE[2]+redE[3]);
        atomicAdd(accum+3, redN[0]+redN[1]+redN[2]+redN[3]);
    }
}

__global__ void final_kernel(const float* __restrict__ accum, float* __restrict__ out)
{
    float logp = -accum[2];
    float m1 = accum[0] * (1.0f / (float)M3);
    float m2 = accum[1] * (1.0f / (float)(N_TOK*LDIM));
    float loss = (m1*0.25f + m1) + (m2*0.25f + m2) + 0.1f*logp;
    out[M3+0] = loss;
    out[M3+1] = expf(logp);
    out[M3+2] = (accum[3] / (float)VNUM) / (float)KSEL;
}

extern "C" void kernel_launch(void* const* d_in, const int* in_sizes, int n_in,
                              void* d_out, int out_size, void* d_ws, size_t ws_size,
                              hipStream_t stream)
{
    const float* x      = (const float*)d_in[0];
    const float* cb     = (const float*)d_in[1];
    const float* W_in   = (const float*)d_in[2];
    const float* b_in   = (const float*)d_in[3];
    const float* W_code = (const float*)d_in[4];
    const float* b_code = (const float*)d_in[5];
    float* out = (float*)d_out;
    float* w   = (float*)d_ws;

    float* zi_pre = w + WS_ZI_PRE;
    float* zi     = w + WS_ZI;
    unsigned short* zib = (unsigned short*)(w + WS_ZIB);
    float* zc     = w + WS_ZC;
    unsigned short* zcb = (unsigned short*)(w + WS_ZCB);
    float* quant  = w + WS_QUANT;
    int*   cand   = (int*)(w + WS_CAND);
    int*   idx4   = (int*)(w + WS_IDX);
    float* counts = w + WS_COUNTS;
    float* accum  = w + WS_ACCUM;

    hipMemsetAsync(counts, 0, (VPAD + 8)*sizeof(float), stream);

    // zi_pre / zi (fp32 exact) + zib (bf16 row-major)
    gemm_k<<<N_TOK/64, 256, 0, stream>>>(x, W_in, b_in, zi_pre, zi, zib,
                                         nullptr, nullptr, N_TOK, 1);
    // zc fp32 (exact path) + zcb bf16 (tiled+swizzled filter path)
    gemm_k<<<VPAD/64, 256, 0, stream>>>(cb, W_code, b_code, nullptr, zc, zcb,
                                        nullptr, nullptr, VNUM, 2);
    // bf16 MFMA candidate filter (dbuf pipelined)
    filter_kernel<<<dim3(N_TOK/QBLK, NGRP), 512, 0, stream>>>(zib, zcb, cand);
    // exact fp32 rescore -> top-4 indices
    rescore_kernel<<<N_TOK, 256, 0, stream>>>(zi, zc, cand, idx4);
    // quantized, out (STE), counts, loss1  (quant overlays dead zcb)
    gather_kernel<<<N_TOK, 192, 0, stream>>>(x, cb, idx4, quant, out, counts, accum);
    // entropy / usage
    stats_kernel<<<(VNUM + 255)/256, 256, 0, stream>>>(counts, accum);
    // loss2: sum((quant@W_code+b_code - zi_pre)^2)
    gemm_k<<<N_TOK/64, 256, 0, stream>>>(quant, W_code, b_code, nullptr, nullptr, nullptr,
                                         zi_pre, accum+1, N_TOK, 3);
    final_kernel<<<1, 1, 0, stream>>>(accum, out);
}

// Round 5
// 1055.583 us; speedup vs baseline: 1.2018x; 1.1748x over previous
//
#include <hip/hip_runtime.h>
#include <math.h>

#define N_TOK 4096
#define DDIM  768
#define LDIM  256
#define VNUM  50265
#define VPAD  50304      // 786 tiles of 64 cols
#define NT64  786
#define NGRP  16
#define QBLK  128
#define KSEL  4
#define M3    3145728    // N_TOK*DDIM

// workspace layout (float offsets), total ~89 MB
#define WS_ZI_PRE 0
#define WS_ZI     (WS_ZI_PRE + N_TOK*LDIM)
#define WS_ZIB    (WS_ZI + N_TOK*LDIM)               // zi bf16 (N_TOK*LDIM/2 floats)
#define WS_ZC     (WS_ZIB + N_TOK*LDIM/2)
#define WS_ZCB    (WS_ZC + VPAD*LDIM)                // zc bf16, tiled+swizzled
#define WS_QUANT  WS_ZCB                             // quant overlays zcb (dead after filter)
#define WS_CAND   (WS_ZCB + VPAD*LDIM/2)
#define WS_IDX    (WS_CAND + N_TOK*64)
#define WS_COUNTS (WS_IDX + N_TOK*4)
#define WS_ACCUM  (WS_COUNTS + VPAD)

typedef __attribute__((ext_vector_type(8))) short short8;
typedef __attribute__((ext_vector_type(4))) float f32x4;

__device__ __forceinline__ unsigned short f2bf(float f) {
    unsigned u = __float_as_uint(f);
    u += 0x7fffu + ((u >> 16) & 1u);
    return (unsigned short)(u >> 16);
}

__device__ __forceinline__ bool better(float v1, int i1, float v2, int i2) {
    return (v1 > v2) || (v1 == v2 && i1 < i2);
}

template<int K>
__device__ __forceinline__ void insertK(float (&v)[K], int (&ix)[K], float nv, int ni) {
    if (!better(nv, ni, v[K-1], ix[K-1])) return;
    v[K-1] = nv; ix[K-1] = ni;
    #pragma unroll
    for (int j = K-1; j > 0; j--) {
        if (better(v[j], ix[j], v[j-1], ix[j-1])) {
            float tv = v[j]; v[j] = v[j-1]; v[j-1] = tv;
            int ti = ix[j]; ix[j] = ix[j-1]; ix[j-1] = ti;
        } else break;
    }
}

// value-only branchless sorted top-3 insert (filter only; ties measure-zero)
__device__ __forceinline__ void ins3(float (&v)[3], int (&ix)[3], float nv, int ni) {
    bool c2 = nv > v[2], c1 = nv > v[1], c0 = nv > v[0];
    v[2]  = c1 ? v[1]  : (c2 ? nv : v[2]);
    ix[2] = c1 ? ix[1] : (c2 ? ni : ix[2]);
    v[1]  = c0 ? v[0]  : (c1 ? nv : v[1]);
    ix[1] = c0 ? ix[0] : (c1 ? ni : ix[1]);
    v[0]  = c0 ? nv : v[0];
    ix[0] = c0 ? ni : ix[0];
}

// Generic C[M,256] = A[M,768] @ W[768,256] + bias, with epilogues:
// mode 1: write pre + l2-normalized fp32 + plain row-major bf16
// mode 2: write normalized fp32 + bf16 in TILED+SWIZZLED chunk layout
// mode 3: accumulate sum((pre-target)^2) -> accum_slot
__global__ __launch_bounds__(256) void gemm_k(
    const float* __restrict__ A, const float* __restrict__ W,
    const float* __restrict__ bias, float* __restrict__ out_pre,
    float* __restrict__ out_norm, unsigned short* __restrict__ out_bf,
    const float* __restrict__ target, float* __restrict__ accum_slot,
    int M, int mode)
{
    __shared__ float a_s[32*64];    // [k][m]
    __shared__ float w_s[32*256];   // [k][n]
    const int tid = threadIdx.x;
    const int tx = tid & 31, ty = tid >> 5;
    const int mbase = blockIdx.x * 64;

    float acc[8][8];
    #pragma unroll
    for (int i = 0; i < 8; i++)
        #pragma unroll
        for (int j = 0; j < 8; j++) acc[i][j] = 0.f;

    for (int kk = 0; kk < DDIM; kk += 32) {
        __syncthreads();
        #pragma unroll
        for (int s = 0; s < 2; s++) {
            int slot = tid + s*256;
            int row = slot >> 3, kc = (slot & 7) << 2;
            int gr = mbase + row; if (gr >= M) gr = M - 1;
            float4 v = *(const float4*)&A[(size_t)gr*DDIM + kk + kc];
            a_s[(kc+0)*64 + row] = v.x;
            a_s[(kc+1)*64 + row] = v.y;
            a_s[(kc+2)*64 + row] = v.z;
            a_s[(kc+3)*64 + row] = v.w;
        }
        #pragma unroll
        for (int s = 0; s < 8; s++) {
            int slot = tid + s*256;
            int r = slot >> 6, c = (slot & 63) << 2;
            *(float4*)&w_s[r*256 + c] = *(const float4*)&W[(size_t)(kk + r)*LDIM + c];
        }
        __syncthreads();
        #pragma unroll
        for (int k = 0; k < 32; k++) {
            float4 a0 = *(float4*)&a_s[k*64 + ty*8];
            float4 a1 = *(float4*)&a_s[k*64 + ty*8 + 4];
            float4 w0 = *(float4*)&w_s[k*256 + tx*4];
            float4 w1 = *(float4*)&w_s[k*256 + 128 + tx*4];
            float am[8] = {a0.x,a0.y,a0.z,a0.w,a1.x,a1.y,a1.z,a1.w};
            float wn[8] = {w0.x,w0.y,w0.z,w0.w,w1.x,w1.y,w1.z,w1.w};
            #pragma unroll
            for (int i = 0; i < 8; i++)
                #pragma unroll
                for (int j = 0; j < 8; j++)
                    acc[i][j] = fmaf(am[i], wn[j], acc[i][j]);
        }
    }

    float bn[8];
    #pragma unroll
    for (int j = 0; j < 8; j++) {
        int col = (j < 4) ? (tx*4 + j) : (128 + tx*4 + (j-4));
        bn[j] = bias[col];
    }
    #pragma unroll
    for (int i = 0; i < 8; i++)
        #pragma unroll
        for (int j = 0; j < 8; j++) acc[i][j] += bn[j];

    if (mode == 1) {
        #pragma unroll
        for (int i = 0; i < 8; i++) {
            int gr = mbase + ty*8 + i;
            if (gr < M) {
                *(float4*)&out_pre[(size_t)gr*LDIM + tx*4] =
                    make_float4(acc[i][0], acc[i][1], acc[i][2], acc[i][3]);
                *(float4*)&out_pre[(size_t)gr*LDIM + 128 + tx*4] =
                    make_float4(acc[i][4], acc[i][5], acc[i][6], acc[i][7]);
            }
        }
    }
    if (mode == 1 || mode == 2) {
        #pragma unroll
        for (int i = 0; i < 8; i++) {
            float s = 0.f;
            #pragma unroll
            for (int j = 0; j < 8; j++) s += acc[i][j]*acc[i][j];
            #pragma unroll
            for (int m = 16; m >= 1; m >>= 1) s += __shfl_xor(s, m, 64);
            float sc = 1.0f / sqrtf(s + 1e-12f);
            int gr = mbase + ty*8 + i;
            bool wr = (mode == 2) || (gr < M);
            if (wr) {
                float p[8];
                #pragma unroll
                for (int j = 0; j < 8; j++) p[j] = acc[i][j]*sc;
                *(float4*)&out_norm[(size_t)gr*LDIM + tx*4] = make_float4(p[0],p[1],p[2],p[3]);
                *(float4*)&out_norm[(size_t)gr*LDIM + 128 + tx*4] = make_float4(p[4],p[5],p[6],p[7]);
                if (out_bf) {
                    ushort4 b0, b1;
                    b0.x = f2bf(p[0]); b0.y = f2bf(p[1]); b0.z = f2bf(p[2]); b0.w = f2bf(p[3]);
                    b1.x = f2bf(p[4]); b1.y = f2bf(p[5]); b1.z = f2bf(p[6]); b1.w = f2bf(p[7]);
                    if (mode == 1) {
                        *(ushort4*)&out_bf[(size_t)gr*LDIM + tx*4] = b0;
                        *(ushort4*)&out_bf[(size_t)gr*LDIM + 128 + tx*4] = b1;
                    } else {
                        // tiled+swizzled: chunk ck=(T*4+kc) is 8KB contiguous;
                        // slot(c,seg) = c*8 + (seg ^ (c&7)), 8 elems each.
                        const int T = gr >> 6, c = gr & 63;
                        #pragma unroll
                        for (int h = 0; h < 2; h++) {
                            const int k0 = h*128 + tx*4;
                            const int kc = k0 >> 6, seg = (k0 >> 3) & 7, e = k0 & 7;
                            const int slot = c*8 + (seg ^ (c & 7));
                            size_t idx = ((size_t)(T*4 + kc))*4096 + slot*8 + e;
                            *(ushort4*)&out_bf[idx] = h ? b1 : b0;
                        }
                    }
                }
            }
        }
    }
    if (mode == 3) {
        float ls = 0.f;
        #pragma unroll
        for (int i = 0; i < 8; i++) {
            int gr = mbase + ty*8 + i;
            if (gr < M) {
                #pragma unroll
                for (int j = 0; j < 8; j++) {
                    int col = (j < 4) ? (tx*4 + j) : (128 + tx*4 + (j-4));
                    float dd = acc[i][j] - target[(size_t)gr*LDIM + col];
                    ls = fmaf(dd, dd, ls);
                }
            }
        }
        #pragma unroll
        for (int off = 32; off >= 1; off >>= 1) ls += __shfl_down(ls, off, 64);
        __syncthreads();
        if ((tid & 63) == 0) a_s[tid >> 6] = ls;
        __syncthreads();
        if (tid == 0) atomicAdd(accum_slot, a_s[0]+a_s[1]+a_s[2]+a_s[3]);
    }
}

// ---------------- bf16 MFMA filter ----------------
// Block: 4 waves x 32 q = 128 q; grid (32, 16) = 512 blocks -> 2 blocks/CU so
// one block's barrier stall overlaps the other's compute. Chunk = 64 cols x
// 64 k bf16 = 8 KB, contiguous+pre-swizzled in zcb; reg->ds_write dbuf.
__global__ __launch_bounds__(256, 2) void filter_kernel(
    const unsigned short* __restrict__ zib, const unsigned short* __restrict__ zcb,
    int* __restrict__ cand)
{
    __shared__ unsigned short lds[2*4096];      // 2 x 8 KB
    const int tid = threadIdx.x;
    const int wave = tid >> 6, lane = tid & 63;
    const int l15 = lane & 15, l4 = lane >> 4;
    const int qbase = blockIdx.x * QBLK + wave * 32;
    const int g = blockIdx.y;                   // 0..15

    // A fragments (zi bf16) resident: [qtile][kstep], 64 VGPRs
    short8 afrag[2][8];
    #pragma unroll
    for (int qt = 0; qt < 2; qt++)
        #pragma unroll
        for (int ks = 0; ks < 8; ks++)
            afrag[qt][ks] = *(const short8*)&zib[(size_t)(qbase + qt*16 + l15)*LDIM + ks*32 + l4*8];

    float tv[2][4][3]; int tix[2][4][3];
    #pragma unroll
    for (int qt = 0; qt < 2; qt++)
        #pragma unroll
        for (int rr = 0; rr < 4; rr++)
            #pragma unroll
            for (int j = 0; j < 3; j++) { tv[qt][rr][j] = -1e30f; tix[qt][rr][j] = 0x7fffffff; }

    f32x4 acc[2][4];
    #pragma unroll
    for (int qt = 0; qt < 2; qt++)
        #pragma unroll
        for (int tc = 0; tc < 4; tc++) acc[qt][tc] = (f32x4)(0.f);

    const int nct = (g < 2) ? 50 : 49;          // 786 = 49*16 + 2
    const int NCk = nct * 4;

    // chunk ci -> ushort offset (8KB contiguous chunks, pre-swizzled)
    #define CHUNK_OFF(ci) ((size_t)((g + ((ci) >> 2)*NGRP)*4 + ((ci) & 3)) * 4096)

    // 256 threads stage 8 KB as two coalesced 4 KB planes
    uint4 br0, br1;
    br0 = *(const uint4*)&zcb[CHUNK_OFF(0) + tid*8];
    br1 = *(const uint4*)&zcb[CHUNK_OFF(0) + 2048 + tid*8];
    *(uint4*)&lds[tid*8] = br0;
    *(uint4*)&lds[2048 + tid*8] = br1;
    br0 = *(const uint4*)&zcb[CHUNK_OFF(1) + tid*8];
    br1 = *(const uint4*)&zcb[CHUNK_OFF(1) + 2048 + tid*8];
    __syncthreads();

    for (int ci = 0; ci < NCk; ci++) {
        const unsigned short* lb = &lds[(ci & 1)*4096];
        #pragma unroll
        for (int ks2 = 0; ks2 < 2; ks2++) {
            const int kf = (ci & 3)*2 + ks2;
            #pragma unroll
            for (int tc = 0; tc < 4; tc++) {
                const int c = tc*16 + l15;
                const int slot = c*8 + ((ks2*4 + l4) ^ (c & 7));
                const short8 b = *(const short8*)&lb[slot*8];
                acc[0][tc] = __builtin_amdgcn_mfma_f32_16x16x32_bf16(afrag[0][kf], b, acc[0][tc], 0, 0, 0);
                acc[1][tc] = __builtin_amdgcn_mfma_f32_16x16x32_bf16(afrag[1][kf], b, acc[1][tc], 0, 0, 0);
            }
        }

        if ((ci & 3) == 3) {                    // tile finished (k=256 done)
            const int T = g + (ci >> 2)*NGRP;
            #pragma unroll
            for (int tc = 0; tc < 4; tc++) {
                const int col = T*64 + tc*16 + l15;
                const bool ok = col < VNUM;
                #pragma unroll
                for (int qt = 0; qt < 2; qt++) {
                    #pragma unroll
                    for (int rr = 0; rr < 4; rr++) {
                        float v = ok ? acc[qt][tc][rr] : -1e30f;
                        ins3(tv[qt][rr], tix[qt][rr], v, col);
                    }
                    acc[qt][tc] = (f32x4)(0.f);
                }
            }
        }

        __syncthreads();                        // readers of other buffer done
        if (ci + 1 < NCk) {
            *(uint4*)&lds[((ci+1) & 1)*4096 + tid*8] = br0;
            *(uint4*)&lds[((ci+1) & 1)*4096 + 2048 + tid*8] = br1;
            if (ci + 2 < NCk) {
                br0 = *(const uint4*)&zcb[CHUNK_OFF(ci+2) + tid*8];
                br1 = *(const uint4*)&zcb[CHUNK_OFF(ci+2) + 2048 + tid*8];
            }
            __syncthreads();                    // next buffer ready
        }
    }
    #undef CHUNK_OFF

    // merge per-lane-class top-3 across the 16 col-lanes (butterfly in-quad)
    #pragma unroll
    for (int qt = 0; qt < 2; qt++)
        #pragma unroll
        for (int rr = 0; rr < 4; rr++) {
            float mv[4] = { tv[qt][rr][0], tv[qt][rr][1], tv[qt][rr][2], -1e30f };
            int   mi[4] = { tix[qt][rr][0], tix[qt][rr][1], tix[qt][rr][2], 0x7fffffff };
            #pragma unroll
            for (int m = 1; m < 16; m <<= 1) {
                float ov[4]; int oi[4];
                #pragma unroll
                for (int s = 0; s < 4; s++) {
                    ov[s] = __shfl_xor(mv[s], m, 64);
                    oi[s] = __shfl_xor(mi[s], m, 64);
                }
                #pragma unroll
                for (int s = 0; s < 4; s++) insertK<4>(mv, mi, ov[s], oi[s]);
            }
            if (l15 == 0) {
                const int q = qbase + qt*16 + l4*4 + rr;
                #pragma unroll
                for (int j = 0; j < 4; j++) cand[(size_t)q*64 + g*4 + j] = mi[j];
            }
        }
}

// exact fp32 rescore of 64 candidates/query; top-4 with ref tie-breaking
__global__ __launch_bounds__(256) void rescore_kernel(
    const float* __restrict__ zi, const float* __restrict__ zc,
    const int* __restrict__ cand, int* __restrict__ idx4)
{
    __shared__ float zi_s[256];
    __shared__ float sval[64];
    __shared__ int   sidx[64];
    const int q = blockIdx.x;
    const int t = threadIdx.x;
    if (t < 64) *(float4*)&zi_s[t*4] = *(const float4*)&zi[(size_t)q*LDIM + t*4];
    __syncthreads();

    const int j = t >> 2, l4 = t & 3;
    int idx = cand[(size_t)q*64 + j];
    const bool valid = (unsigned)idx < (unsigned)VNUM;
    const float* r = zc + (size_t)(valid ? idx : 0)*LDIM;
    float dot = 0.f, nsq = 0.f;
    #pragma unroll
    for (int i = 0; i < 16; i++) {
        float4 v = *(const float4*)&r[i*16 + l4*4];
        float4 z = *(const float4*)&zi_s[i*16 + l4*4];
        dot = fmaf(v.x, z.x, fmaf(v.y, z.y, fmaf(v.z, z.z, fmaf(v.w, z.w, dot))));
        nsq = fmaf(v.x, v.x, fmaf(v.y, v.y, fmaf(v.z, v.z, fmaf(v.w, v.w, nsq))));
    }
    dot += __shfl_xor(dot, 1, 64); dot += __shfl_xor(dot, 2, 64);
    nsq += __shfl_xor(nsq, 1, 64); nsq += __shfl_xor(nsq, 2, 64);
    const float sc = valid ? (dot - 0.5f*nsq) : -1e30f;
    if (l4 == 0) { sval[j] = sc; sidx[j] = valid ? idx : 0x7fffffff; }
    __syncthreads();

    if (t < 64) {
        float v[4] = {-1e30f, -1e30f, -1e30f, -1e30f};
        int ix[4] = {0x7fffffff, 0x7fffffff, 0x7fffffff, 0x7fffffff};
        insertK<4>(v, ix, sval[t], sidx[t]);
        #pragma unroll
        for (int m = 1; m < 64; m <<= 1) {
            float ov[4]; int oi[4];
            #pragma unroll
            for (int s = 0; s < 4; s++) {
                ov[s] = __shfl_xor(v[s], m, 64);
                oi[s] = __shfl_xor(ix[s], m, 64);
            }
            #pragma unroll
            for (int s = 0; s < 4; s++) insertK<4>(v, ix, ov[s], oi[s]);
        }
        if (t == 0) {
            #pragma unroll
            for (int s = 0; s < 4; s++) idx4[q*4 + s] = ix[s];
        }
    }
}

// gather codes, mean-of-4, STE out, counts atomics, loss1 partial
__global__ __launch_bounds__(192) void gather_kernel(
    const float* __restrict__ x, const float* __restrict__ cb,
    const int* __restrict__ idx4, float* __restrict__ quant,
    float* __restrict__ out, float* __restrict__ counts,
    float* __restrict__ accum)
{
    __shared__ float red[3];
    const int n = blockIdx.x;
    const int t = threadIdx.x;
    const int i0 = idx4[n*4+0], i1 = idx4[n*4+1], i2 = idx4[n*4+2], i3 = idx4[n*4+3];
    if (t < 4) atomicAdd(&counts[idx4[n*4+t]], 1.0f);
    const int d = t*4;
    float4 c0 = *(const float4*)&cb[(size_t)i0*DDIM + d];
    float4 c1 = *(const float4*)&cb[(size_t)i1*DDIM + d];
    float4 c2 = *(const float4*)&cb[(size_t)i2*DDIM + d];
    float4 c3 = *(const float4*)&cb[(size_t)i3*DDIM + d];
    float4 xv = *(const float4*)&x[(size_t)n*DDIM + d];
    float4 qv;
    qv.x = (((c0.x + c1.x) + c2.x) + c3.x) * 0.25f;
    qv.y = (((c0.y + c1.y) + c2.y) + c3.y) * 0.25f;
    qv.z = (((c0.z + c1.z) + c2.z) + c3.z) * 0.25f;
    qv.w = (((c0.w + c1.w) + c2.w) + c3.w) * 0.25f;
    float4 o;
    o.x = xv.x + (qv.x - xv.x);
    o.y = xv.y + (qv.y - xv.y);
    o.z = xv.z + (qv.z - xv.z);
    o.w = xv.w + (qv.w - xv.w);
    *(float4*)&quant[(size_t)n*DDIM + d] = qv;
    *(float4*)&out[(size_t)n*DDIM + d] = o;
    float d0 = qv.x - xv.x, d1 = qv.y - xv.y, d2 = qv.z - xv.z, d3 = qv.w - xv.w;
    float ls = d0*d0 + d1*d1 + d2*d2 + d3*d3;
    #pragma unroll
    for (int off = 32; off >= 1; off >>= 1) ls += __shfl_down(ls, off, 64);
    if ((t & 63) == 0) red[t >> 6] = ls;
    __syncthreads();
    if (t == 0) atomicAdd(accum, red[0] + red[1] + red[2]);
}

__global__ __launch_bounds__(256) void stats_kernel(
    const float* __restrict__ counts, float* __restrict__ accum)
{
    __shared__ float redE[4], redN[4];
    int v = blockIdx.x*256 + threadIdx.x;
    float ent = 0.f, nnz = 0.f;
    if (v < VNUM) {
        float c = counts[v];
        if (c > 0.f) {
            float p = c * (1.0f/16384.0f);
            ent = p * logf(p + 1e-10f);
            nnz = 1.f;
        }
    }
    #pragma unroll
    for (int off = 32; off >= 1; off >>= 1) {
        ent += __shfl_down(ent, off, 64);
        nnz += __shfl_down(nnz, off, 64);
    }
    int t = threadIdx.x;
    if ((t & 63) == 0) { redE[t>>6] = ent; redN[t>>6] = nnz; }
    __syncthreads();
    if (t == 0) {
        atomicAdd(accum+2, redE[0]+redE[1]+redE[2]+redE[3]);
        atomicAdd(accum+3, redN[0]+redN[1]+redN[2]+redN[3]);
    }
}

__global__ void final_kernel(const float* __restrict__ accum, float* __restrict__ out)
{
    float logp = -accum[2];
    float m1 = accum[0] * (1.0f / (float)M3);
    float m2 = accum[1] * (1.0f / (float)(N_TOK*LDIM));
    float loss = (m1*0.25f + m1) + (m2*0.25f + m2) + 0.1f*logp;
    out[M3+0] = loss;
    out[M3+1] = expf(logp);
    out[M3+2] = (accum[3] / (float)VNUM) / (float)KSEL;
}

extern "C" void kernel_launch(void* const* d_in, const int* in_sizes, int n_in,
                              void* d_out, int out_size, void* d_ws, size_t ws_size,
                              hipStream_t stream)
{
    const float* x      = (const float*)d_in[0];
    const float* cb     = (const float*)d_in[1];
    const float* W_in   = (const float*)d_in[2];
    const float* b_in   = (const float*)d_in[3];
    const float* W_code = (const float*)d_in[4];
    const float* b_code = (const float*)d_in[5];
    float* out = (float*)d_out;
    float* w   = (float*)d_ws;

    float* zi_pre = w + WS_ZI_PRE;
    float* zi     = w + WS_ZI;
    unsigned short* zib = (unsigned short*)(w + WS_ZIB);
    float* zc     = w + WS_ZC;
    unsigned short* zcb = (unsigned short*)(w + WS_ZCB);
    float* quant  = w + WS_QUANT;
    int*   cand   = (int*)(w + WS_CAND);
    int*   idx4   = (int*)(w + WS_IDX);
    float* counts = w + WS_COUNTS;
    float* accum  = w + WS_ACCUM;

    hipMemsetAsync(counts, 0, (VPAD + 8)*sizeof(float), stream);

    // zi_pre / zi (fp32 exact) + zib (bf16 row-major)
    gemm_k<<<N_TOK/64, 256, 0, stream>>>(x, W_in, b_in, zi_pre, zi, zib,
                                         nullptr, nullptr, N_TOK, 1);
    // zc fp32 (exact path) + zcb bf16 (tiled+swizzled filter path)
    gemm_k<<<VPAD/64, 256, 0, stream>>>(cb, W_code, b_code, nullptr, zc, zcb,
                                        nullptr, nullptr, VNUM, 2);
    // bf16 MFMA candidate filter (dbuf pipelined, 2 blocks/CU)
    filter_kernel<<<dim3(N_TOK/QBLK, NGRP), 256, 0, stream>>>(zib, zcb, cand);
    // exact fp32 rescore -> top-4 indices
    rescore_kernel<<<N_TOK, 256, 0, stream>>>(zi, zc, cand, idx4);
    // quantized, out (STE), counts, loss1  (quant overlays dead zcb)
    gather_kernel<<<N_TOK, 192, 0, stream>>>(x, cb, idx4, quant, out, counts, accum);
    // entropy / usage
    stats_kernel<<<(VNUM + 255)/256, 256, 0, stream>>>(counts, accum);
    // loss2: sum((quant@W_code+b_code - zi_pre)^2)
    gemm_k<<<N_TOK/64, 256, 0, stream>>>(quant, W_code, b_code, nullptr, nullptr, nullptr,
                                         zi_pre, accum+1, N_TOK, 3);
    final_kernel<<<1, 1, 0, stream>>>(accum, out);
}